// Round 1
// baseline (79.218 us; speedup 1.0000x reference)
//
#include <hip/hip_runtime.h>
#include <hip/hip_bf16.h>

// Problem: out[b,s,c] = x[b,s,:] @ W, W[r][c] = kernel[(r%512)*4096 + c]
// Restructured: xr[m][r'] = sum_{i<8} x[m][r'+512*i]  (M=8192, K'=512)
//               out = xr @ K  with K[r'][c] = kernel[r'*4096+c]
// All GEMM inputs cast to bf16; MFMA f32_16x16x32_bf16; fp32 accumulate.

#define M_TOT   8192
#define N_TOT   4096
#define K_RED   512
#define K_FULL  4096

typedef __attribute__((ext_vector_type(8))) short bf16x8;
typedef __attribute__((ext_vector_type(4))) float f32x4;
typedef __attribute__((ext_vector_type(4))) unsigned short u16x4;

static __device__ __forceinline__ unsigned short f2bf(float f) {
    unsigned int u = __float_as_uint(f);
    unsigned int r = (u + 0x7fffu + ((u >> 16) & 1u)) >> 16;
    return (unsigned short)r;
}

// ---------------------------------------------------------------------------
// Kernel 1: Bt[c][r'] = bf16(kernel[r'*4096 + c])   (transpose via LDS tile)
// grid (4096/64, 512/64) = (64, 8), block 256
// ---------------------------------------------------------------------------
__global__ __launch_bounds__(256) void build_bt(const int* __restrict__ kin,
                                                unsigned short* __restrict__ bt) {
    __shared__ unsigned short tile[64][65];
    const int c0 = blockIdx.x * 64;
    const int r0 = blockIdx.y * 64;
    const int tx = threadIdx.x & 63;
    const int ty = threadIdx.x >> 6;   // 0..3
#pragma unroll
    for (int rr = 0; rr < 64; rr += 4) {
        int r = r0 + rr + ty;
        tile[rr + ty][tx] = f2bf((float)kin[(size_t)r * N_TOT + c0 + tx]);
    }
    __syncthreads();
#pragma unroll
    for (int cc = 0; cc < 64; cc += 4) {
        int c = c0 + cc + ty;
        bt[(size_t)c * K_RED + r0 + tx] = tile[tx][cc + ty];
    }
}

// ---------------------------------------------------------------------------
// Kernel 2: xr[m][r'] = bf16( sum_{i<8} x[m][r' + 512*i] )
// grid 4096 (2 rows/block), block 256; float4 loads, ushort4 stores
// ---------------------------------------------------------------------------
__global__ __launch_bounds__(256) void reduce8(const float* __restrict__ x,
                                               unsigned short* __restrict__ xr) {
    const int row = blockIdx.x * 2 + (threadIdx.x >> 7);
    const int t2  = threadIdx.x & 127;          // handles r' = 4*t2 .. 4*t2+3
    const float* xp = x + (size_t)row * K_FULL + t2 * 4;
    float a0 = 0.f, a1 = 0.f, a2 = 0.f, a3 = 0.f;
#pragma unroll
    for (int i = 0; i < 8; ++i) {
        float4 v = *reinterpret_cast<const float4*>(xp + (size_t)i * K_RED);
        a0 += v.x; a1 += v.y; a2 += v.z; a3 += v.w;
    }
    u16x4 o;
    o.x = f2bf(a0); o.y = f2bf(a1); o.z = f2bf(a2); o.w = f2bf(a3);
    *reinterpret_cast<u16x4*>(xr + (size_t)row * K_RED + t2 * 4) = o;
}

// ---------------------------------------------------------------------------
// Kernel 3: GEMM  C[8192][4096] f32 = A[8192][512] bf16  @  Bt[4096][512]^T
// 128x128 tile, BK=64, 256 threads = 4 waves (2x2), global_load_lds width 16
// ---------------------------------------------------------------------------
#define BM 128
#define BN 128
#define BK 64

__global__ __launch_bounds__(256, 2) void gemm512(const unsigned short* __restrict__ A,
                                                  const unsigned short* __restrict__ Bt,
                                                  float* __restrict__ C) {
    __shared__ unsigned short As[BM * BK];   // [row][k]  row-major, 16 KB
    __shared__ unsigned short Bs[BN * BK];   // [col][k]  row-major, 16 KB

    const int tid  = threadIdx.x;
    const int lane = tid & 63;
    const int w    = tid >> 6;       // wave 0..3
    const int wr   = w >> 1;         // wave row 0..1
    const int wc   = w & 1;          // wave col 0..1
    const int m0   = blockIdx.y * BM;
    const int n0   = blockIdx.x * BN;
    const int l15  = lane & 15;
    const int lhi  = lane >> 4;

    f32x4 acc[4][4] = {};

    for (int kt = 0; kt < K_RED / BK; ++kt) {
        __syncthreads();   // previous compute done before overwriting LDS
#pragma unroll
        for (int it = 0; it < 4; ++it) {
            const int seg = it * 4 + w;            // 0..15 (wave-uniform)
            const int eo  = (seg * 64 + lane) * 8; // bf16 element offset in tile
            const int row = eo >> 6;               // /64
            const int col = eo & 63;
            const unsigned short* ga = A  + (size_t)(m0 + row) * K_RED + kt * BK + col;
            const unsigned short* gb = Bt + (size_t)(n0 + row) * K_RED + kt * BK + col;
            __builtin_amdgcn_global_load_lds(
                (__attribute__((address_space(1))) void*)ga,
                (__attribute__((address_space(3))) void*)&As[seg * 512],
                16, 0, 0);
            __builtin_amdgcn_global_load_lds(
                (__attribute__((address_space(1))) void*)gb,
                (__attribute__((address_space(3))) void*)&Bs[seg * 512],
                16, 0, 0);
        }
        __syncthreads();   // drains vmcnt before barrier (compiler-inserted)
#pragma unroll
        for (int ks = 0; ks < 2; ++ks) {
            bf16x8 af[4], bfr[4];
#pragma unroll
            for (int mi = 0; mi < 4; ++mi)
                af[mi] = *reinterpret_cast<const bf16x8*>(
                    &As[(wr * 64 + mi * 16 + l15) * BK + ks * 32 + lhi * 8]);
#pragma unroll
            for (int ni = 0; ni < 4; ++ni)
                bfr[ni] = *reinterpret_cast<const bf16x8*>(
                    &Bs[(wc * 64 + ni * 16 + l15) * BK + ks * 32 + lhi * 8]);
#pragma unroll
            for (int mi = 0; mi < 4; ++mi)
#pragma unroll
                for (int ni = 0; ni < 4; ++ni)
                    acc[mi][ni] = __builtin_amdgcn_mfma_f32_16x16x32_bf16(
                        af[mi], bfr[ni], acc[mi][ni], 0, 0, 0);
        }
    }

    // Epilogue: C/D layout col = lane&15, row = (lane>>4)*4 + reg  [m89/m91]
#pragma unroll
    for (int mi = 0; mi < 4; ++mi) {
#pragma unroll
        for (int ni = 0; ni < 4; ++ni) {
            f32x4 v = acc[mi][ni];
            const int col  = n0 + wc * 64 + ni * 16 + l15;
            const int rowb = m0 + wr * 64 + mi * 16 + lhi * 4;
#pragma unroll
            for (int r = 0; r < 4; ++r)
                C[(size_t)(rowb + r) * N_TOT + col] = v[r];
        }
    }
}

// ---------------------------------------------------------------------------
extern "C" void kernel_launch(void* const* d_in, const int* in_sizes, int n_in,
                              void* d_out, int out_size, void* d_ws, size_t ws_size,
                              hipStream_t stream) {
    const float* x   = (const float*)d_in[0];       // [2,4096,4096] f32
    const int*   kin = (const int*)d_in[1];         // [2097152] int (values -1..1)
    float*       out = (float*)d_out;               // [2,4096,4096] f32

    unsigned short* xr = (unsigned short*)d_ws;                       // 8 MB
    unsigned short* bt = (unsigned short*)((char*)d_ws + (size_t)M_TOT * K_RED * 2); // 4 MB

    build_bt<<<dim3(N_TOT / 64, K_RED / 64), 256, 0, stream>>>(kin, bt);
    reduce8<<<dim3(M_TOT / 2), 256, 0, stream>>>(x, xr);
    gemm512<<<dim3(N_TOT / BN, M_TOT / BM), 256, 0, stream>>>(xr, bt, out);
}